// Round 1
// baseline (177.162 us; speedup 1.0000x reference)
//
#include <hip/hip_runtime.h>
#include <math.h>

#define Bsz 512
#define NA  128
#define NL  512
#define Dd  128
#define KA  16
#define KL  16

// ---------------------------------------------------------------------------
// Bool-layout detection: jax bool arrays may arrive as 1-byte bools or as
// int32 0/1. If int32, every byte at offset (i&3)!=0 is zero. Real bool
// arrays (~50% ones) have nonzero off-bytes with overwhelming probability.
// flag=1 -> 1-byte bool layout, flag=0 -> int32 layout.
// ---------------------------------------------------------------------------
__global__ __launch_bounds__(256) void detect_bool_kernel(
    const unsigned char* __restrict__ av, int* __restrict__ flag) {
  __shared__ int s;
  if (threadIdx.x == 0) s = 0;
  __syncthreads();
  int any = 0;
  for (int i = threadIdx.x; i < 4096; i += 256)
    if ((i & 3) && av[i]) any = 1;
  if (any) atomicOr(&s, 1);
  __syncthreads();
  if (threadIdx.x == 0) *flag = s;
}

__device__ __forceinline__ int validAt(const unsigned char* p, int i, int isbyte) {
  return isbyte ? (int)p[i] : ((const int*)p)[i];
}

// ---------------------------------------------------------------------------
// Kernel A: per-batch index selection.
//   - top-KA agents by masked spike rate (desc value, asc index tiebreak)
//   - lane_dist[l] = min over selected agents of euclid dist; invalid -> inf
//   - top-KL smallest lane distances (asc value, asc index tiebreak)
// ---------------------------------------------------------------------------
__global__ __launch_bounds__(256) void idx_kernel(
    const float* __restrict__ spike, const unsigned char* __restrict__ avalid,
    const float* __restrict__ xc, const float* __restrict__ lc,
    const unsigned char* __restrict__ lvalid, const int* __restrict__ flagp,
    int* __restrict__ aidx, int* __restrict__ lidx) {
  const int b = blockIdx.x;
  const int tid = threadIdx.x;
  const int isbyte = *flagp;

  __shared__ float s_ax[KA], s_ay[KA];
  __shared__ int   s_ai[KA];
  __shared__ float s_ld[NL];
  __shared__ float s_rv[4];
  __shared__ int   s_ri[4];

  // ---- agent top-16: wave 0 only, 2 candidates per lane ----
  if (tid < 64) {
    float v0 = validAt(avalid, b * NA + tid, isbyte)      ? spike[b * NA + tid]      : -INFINITY;
    float v1 = validAt(avalid, b * NA + tid + 64, isbyte) ? spike[b * NA + tid + 64] : -INFINITY;
    for (int it = 0; it < KA; ++it) {
      float bv = v0; int bi = tid;
      if (v1 > bv) { bv = v1; bi = tid + 64; }   // tie keeps lower index (tid)
      for (int off = 32; off; off >>= 1) {
        float ov = __shfl_xor(bv, off);
        int   oi = __shfl_xor(bi, off);
        if (ov > bv || (ov == bv && oi < bi)) { bv = ov; bi = oi; }
      }
      if (bi == tid)      v0 = -INFINITY;
      if (bi == tid + 64) v1 = -INFINITY;
      if (tid == 0) s_ai[it] = bi;
    }
  }
  __syncthreads();
  if (tid < KA) {
    int a = s_ai[tid];
    aidx[b * KA + tid] = a;
    s_ax[tid] = xc[(b * NA + a) * 2 + 0];
    s_ay[tid] = xc[(b * NA + a) * 2 + 1];
  }
  __syncthreads();

  // ---- lane distances (min of squared dist; sqrt deferred, monotone) ----
  for (int l = tid; l < NL; l += 256) {
    float lx = lc[(b * NL + l) * 2 + 0];
    float ly = lc[(b * NL + l) * 2 + 1];
    float best = INFINITY;
#pragma unroll
    for (int a = 0; a < KA; ++a) {
      float dx = s_ax[a] - lx, dy = s_ay[a] - ly;
      float d2 = __fadd_rn(__fmul_rn(dx, dx), __fmul_rn(dy, dy));  // no fma contraction
      best = fminf(best, d2);
    }
    best = sqrtf(best);
    s_ld[l] = validAt(lvalid, b * NL + l, isbyte) ? best : INFINITY;
  }
  __syncthreads();

  // ---- lane top-16 smallest: block-wide iterative argmin ----
  const int wid = tid >> 6, lane = tid & 63;
  for (int it = 0; it < KL; ++it) {
    float bv = s_ld[tid]; int bi = tid;
    float v2 = s_ld[tid + 256];
    if (v2 < bv) { bv = v2; bi = tid + 256; }    // tie keeps lower index
    for (int off = 32; off; off >>= 1) {
      float ov = __shfl_xor(bv, off);
      int   oi = __shfl_xor(bi, off);
      if (ov < bv || (ov == bv && oi < bi)) { bv = ov; bi = oi; }
    }
    if (lane == 0) { s_rv[wid] = bv; s_ri[wid] = bi; }
    __syncthreads();
    if (tid == 0) {
      float fbv = s_rv[0]; int fbi = s_ri[0];
      for (int w = 1; w < 4; ++w)
        if (s_rv[w] < fbv || (s_rv[w] == fbv && s_ri[w] < fbi)) { fbv = s_rv[w]; fbi = s_ri[w]; }
      lidx[b * KL + it] = fbi;
      s_ld[fbi] = INFINITY;
    }
    __syncthreads();
  }
}

// ---------------------------------------------------------------------------
// Kernel C: gather 32 selected rows, 2x (residual MLP + LayerNorm), scatter.
// Block = 256 (4 waves), one block per batch, each wave owns 8 nodes,
// each lane owns output cols {lane, lane+64}.
// ---------------------------------------------------------------------------
__global__ __launch_bounds__(256) void mlp_kernel(
    const float* __restrict__ actor_feat, const float* __restrict__ lane_feat,
    const int* __restrict__ aidx, const int* __restrict__ lidx,
    const float* __restrict__ W0a, const float* __restrict__ b0a,
    const float* __restrict__ W0b, const float* __restrict__ b0b,
    const float* __restrict__ W1a, const float* __restrict__ b1a,
    const float* __restrict__ W1b, const float* __restrict__ b1b,
    const float* __restrict__ gamma, const float* __restrict__ beta,
    float* __restrict__ out0, float* __restrict__ out1) {
  const int b = blockIdx.x, tid = threadIdx.x;
  __shared__ float s_x[32][Dd];
  __shared__ float s_u[32][Dd];
  __shared__ int   s_src[32];

  if (tid < 16)      s_src[tid] = aidx[b * KA + tid];
  else if (tid < 32) s_src[tid] = lidx[b * KL + (tid - 16)];
  __syncthreads();

  // gather (float4-vectorized): 32 rows x 32 float4
  for (int q = tid; q < 1024; q += 256) {
    int row = q >> 5, c4 = q & 31;
    const float* src = (row < 16)
        ? actor_feat + ((size_t)b * NA + s_src[row]) * Dd
        : lane_feat  + ((size_t)b * NL + s_src[row]) * Dd;
    ((float4*)s_x[row])[c4] = ((const float4*)src)[c4];
  }
  __syncthreads();

  const int lane = tid & 63, w = tid >> 6;
  const int n0 = w * 8;
  const int j0 = lane, j1 = lane + 64;
  const float g0 = gamma[j0], g1 = gamma[j1];
  const float bt0 = beta[j0], bt1 = beta[j1];

  const float* WA[2] = {W0a, W1a}; const float* BA[2] = {b0a, b1a};
  const float* WB[2] = {W0b, W1b}; const float* BB[2] = {b0b, b1b};

  for (int layer = 0; layer < 2; ++layer) {
    const float* wa = WA[layer];
    const float* wb = WB[layer];
    float acc0[8], acc1[8];

    // ---- matvec 1: t = x @ Wa + ba ----
    {
      const float bias0 = BA[layer][j0], bias1 = BA[layer][j1];
#pragma unroll
      for (int n = 0; n < 8; ++n) { acc0[n] = bias0; acc1[n] = bias1; }
#pragma unroll 2
      for (int kk = 0; kk < 32; ++kk) {
        const float w00 = wa[(4 * kk + 0) * Dd + j0], w10 = wa[(4 * kk + 0) * Dd + j1];
        const float w01 = wa[(4 * kk + 1) * Dd + j0], w11 = wa[(4 * kk + 1) * Dd + j1];
        const float w02 = wa[(4 * kk + 2) * Dd + j0], w12 = wa[(4 * kk + 2) * Dd + j1];
        const float w03 = wa[(4 * kk + 3) * Dd + j0], w13 = wa[(4 * kk + 3) * Dd + j1];
#pragma unroll
        for (int n = 0; n < 8; ++n) {
          float4 xv = ((const float4*)s_x[n0 + n])[kk];
          acc0[n] = fmaf(xv.x, w00, acc0[n]); acc1[n] = fmaf(xv.x, w10, acc1[n]);
          acc0[n] = fmaf(xv.y, w01, acc0[n]); acc1[n] = fmaf(xv.y, w11, acc1[n]);
          acc0[n] = fmaf(xv.z, w02, acc0[n]); acc1[n] = fmaf(xv.z, w12, acc1[n]);
          acc0[n] = fmaf(xv.w, w03, acc0[n]); acc1[n] = fmaf(xv.w, w13, acc1[n]);
        }
      }
    }

    // ---- exact GELU -> s_u ----
#pragma unroll
    for (int n = 0; n < 8; ++n) {
      float t0 = acc0[n], t1 = acc1[n];
      s_u[n0 + n][j0] = 0.5f * t0 * (1.0f + erff(t0 * 0.70710678118654752f));
      s_u[n0 + n][j1] = 0.5f * t1 * (1.0f + erff(t1 * 0.70710678118654752f));
    }
    __syncthreads();

    // ---- matvec 2: h = gelu(t) @ Wb + bb ----
    {
      const float bias0 = BB[layer][j0], bias1 = BB[layer][j1];
#pragma unroll
      for (int n = 0; n < 8; ++n) { acc0[n] = bias0; acc1[n] = bias1; }
#pragma unroll 2
      for (int kk = 0; kk < 32; ++kk) {
        const float w00 = wb[(4 * kk + 0) * Dd + j0], w10 = wb[(4 * kk + 0) * Dd + j1];
        const float w01 = wb[(4 * kk + 1) * Dd + j0], w11 = wb[(4 * kk + 1) * Dd + j1];
        const float w02 = wb[(4 * kk + 2) * Dd + j0], w12 = wb[(4 * kk + 2) * Dd + j1];
        const float w03 = wb[(4 * kk + 3) * Dd + j0], w13 = wb[(4 * kk + 3) * Dd + j1];
#pragma unroll
        for (int n = 0; n < 8; ++n) {
          float4 uv = ((const float4*)s_u[n0 + n])[kk];
          acc0[n] = fmaf(uv.x, w00, acc0[n]); acc1[n] = fmaf(uv.x, w10, acc1[n]);
          acc0[n] = fmaf(uv.y, w01, acc0[n]); acc1[n] = fmaf(uv.y, w11, acc1[n]);
          acc0[n] = fmaf(uv.z, w02, acc0[n]); acc1[n] = fmaf(uv.z, w12, acc1[n]);
          acc0[n] = fmaf(uv.w, w03, acc0[n]); acc1[n] = fmaf(uv.w, w13, acc1[n]);
        }
      }
    }

    // ---- residual + LayerNorm (row lives across the wave: 2 cols/lane) ----
#pragma unroll
    for (int n = 0; n < 8; ++n) {
      float r0 = s_x[n0 + n][j0] + acc0[n];
      float r1 = s_x[n0 + n][j1] + acc1[n];
      float sum = r0 + r1;
      for (int off = 32; off; off >>= 1) sum += __shfl_xor(sum, off);
      float mean = sum * (1.0f / 128.0f);
      float d0 = r0 - mean, d1 = r1 - mean;
      float sq = d0 * d0 + d1 * d1;
      for (int off = 32; off; off >>= 1) sq += __shfl_xor(sq, off);
      float inv = 1.0f / sqrtf(sq * (1.0f / 128.0f) + 1e-5f);
      s_x[n0 + n][j0] = d0 * inv * g0 + bt0;
      s_x[n0 + n][j1] = d1 * inv * g1 + bt1;
    }
    __syncthreads();
  }

  // scatter
  for (int q = tid; q < 1024; q += 256) {
    int row = q >> 5, c4 = q & 31;
    float* dst = (row < 16)
        ? out0 + ((size_t)b * NA + s_src[row]) * Dd
        : out1 + ((size_t)b * NL + s_src[row]) * Dd;
    ((float4*)dst)[c4] = ((const float4*)s_x[row])[c4];
  }
}

// ---------------------------------------------------------------------------
extern "C" void kernel_launch(void* const* d_in, const int* in_sizes, int n_in,
                              void* d_out, int out_size, void* d_ws, size_t ws_size,
                              hipStream_t stream) {
  const float* actor_feat = (const float*)d_in[0];
  const float* lane_feat  = (const float*)d_in[1];
  const float* lc         = (const float*)d_in[2];
  const float* xc         = (const float*)d_in[3];
  const float* spike      = (const float*)d_in[4];
  const unsigned char* avalid = (const unsigned char*)d_in[5];
  const unsigned char* lvalid = (const unsigned char*)d_in[6];
  const float* W0a = (const float*)d_in[7];
  const float* b0a = (const float*)d_in[8];
  const float* W0b = (const float*)d_in[9];
  const float* b0b = (const float*)d_in[10];
  const float* W1a = (const float*)d_in[11];
  const float* b1a = (const float*)d_in[12];
  const float* W1b = (const float*)d_in[13];
  const float* b1b = (const float*)d_in[14];
  const float* gamma = (const float*)d_in[15];
  const float* beta  = (const float*)d_in[16];

  int* aidx = (int*)d_ws;
  int* lidx = aidx + Bsz * KA;
  int* flag = lidx + Bsz * KL;

  float* out0 = (float*)d_out;
  float* out1 = out0 + (size_t)Bsz * NA * Dd;

  detect_bool_kernel<<<1, 256, 0, stream>>>(avalid, flag);
  idx_kernel<<<Bsz, 256, 0, stream>>>(spike, avalid, xc, lc, lvalid, flag, aidx, lidx);
  hipMemcpyAsync(out0, actor_feat, (size_t)Bsz * NA * Dd * sizeof(float),
                 hipMemcpyDeviceToDevice, stream);
  hipMemcpyAsync(out1, lane_feat, (size_t)Bsz * NL * Dd * sizeof(float),
                 hipMemcpyDeviceToDevice, stream);
  mlp_kernel<<<Bsz, 256, 0, stream>>>(actor_feat, lane_feat, aidx, lidx,
                                      W0a, b0a, W0b, b0b, W1a, b1a, W1b, b1b,
                                      gamma, beta, out0, out1);
}